// Round 5
// baseline (310.780 us; speedup 1.0000x reference)
//
#include <hip/hip_runtime.h>
#include <hip/hip_bf16.h>
#include <stdint.h>

#define T_TOK 4096
#define D_DIM 1024
#define E_NUM 8
#define F_DIM 512
#define SH_DIM 1024
#define SCALE_F 2.5f

#define BM 128
#define BN 128
#define BK 32
#define LDT 40   // padded LDS row stride (bf16 elems): 32 + 8 keeps bank aliasing ~2-way

#define NBIG (E_NUM * F_DIM * D_DIM)   // 4194304
#define NSML (SH_DIM * D_DIM)          // 1048576
#define NCONV_CHUNKS ((3 * NBIG + 3 * NSML) / 4)  // 3932160
#define MAX_TILES 72

typedef unsigned short ushort_t;
typedef __attribute__((ext_vector_type(8))) short short8;
typedef __attribute__((ext_vector_type(4))) short short4v;
typedef __attribute__((ext_vector_type(4))) float f32x4;

__device__ inline ushort_t f2bf(float f) {
  union { float f; unsigned u; } cv; cv.f = f;
  unsigned u = cv.u;
  unsigned r = (u + 0x7FFFu + ((u >> 16) & 1u)) >> 16;  // RNE
  return (ushort_t)r;
}

// ---------------- gate (f32 exact) + x -> bf16 ----------------
__global__ void gate_kernel(const float* __restrict__ x, const float* __restrict__ gw,
                            const float* __restrict__ gb, float* __restrict__ ew,
                            ushort_t* __restrict__ xb) {
  int t = blockIdx.x;
  int lane = threadIdx.x;  // 64 threads
  const float* xr = x + (size_t)t * D_DIM;
  float xv[16];
#pragma unroll
  for (int i = 0; i < 16; i++) xv[i] = xr[lane + (i << 6)];
#pragma unroll
  for (int i = 0; i < 16; i++) xb[(size_t)t * D_DIM + lane + (i << 6)] = f2bf(xv[i]);
  float logit[E_NUM];
#pragma unroll
  for (int e = 0; e < E_NUM; e++) {
    const float* wr = gw + (size_t)e * D_DIM;
    float s = 0.f;
#pragma unroll
    for (int i = 0; i < 16; i++) s += xv[i] * wr[lane + (i << 6)];
#pragma unroll
    for (int off = 32; off; off >>= 1) s += __shfl_xor(s, off, 64);
    logit[e] = s;
  }
  if (lane == 0) {
    float scores[E_NUM], sc[E_NUM];
#pragma unroll
    for (int e = 0; e < E_NUM; e++) {
      scores[e] = 1.f / (1.f + expf(-logit[e]));
      sc[e] = scores[e] + gb[e];
    }
    // group scores: groups of 2 experts, top-2 of 2 = both -> sum
    float gs[4];
#pragma unroll
    for (int g = 0; g < 4; g++) gs[g] = sc[2 * g] + sc[2 * g + 1];
    int g0 = 0;
#pragma unroll
    for (int g = 1; g < 4; g++) if (gs[g] > gs[g0]) g0 = g;
    int g1 = -1;
#pragma unroll
    for (int g = 0; g < 4; g++) { if (g == g0) continue; if (g1 < 0 || gs[g] > gs[g1]) g1 = g; }
    float tmp[E_NUM];
#pragma unroll
    for (int e = 0; e < E_NUM; e++) {
      int g = e >> 1;
      tmp[e] = (g == g0 || g == g1) ? sc[e] : 0.f;
    }
    int e0 = 0;
#pragma unroll
    for (int e = 1; e < E_NUM; e++) if (tmp[e] > tmp[e0]) e0 = e;
    int e1 = -1;
#pragma unroll
    for (int e = 0; e < E_NUM; e++) { if (e == e0) continue; if (e1 < 0 || tmp[e] > tmp[e1]) e1 = e; }
    float w0 = scores[e0], w1v = scores[e1];
    float inv = SCALE_F / (w0 + w1v + 1e-20f);
    float o[E_NUM];
#pragma unroll
    for (int e = 0; e < E_NUM; e++) o[e] = 0.f;
    o[e0] = w0 * inv;
    o[e1] = w1v * inv;
#pragma unroll
    for (int e = 0; e < E_NUM; e++) ew[t * E_NUM + e] = o[e];
  }
}

// ---------------- weight f32 -> bf16 conversion ----------------
__global__ void convert_kernel(const float* __restrict__ w1, const float* __restrict__ w2,
                               const float* __restrict__ w3, const float* __restrict__ sg,
                               const float* __restrict__ su, const float* __restrict__ sd,
                               ushort_t* __restrict__ w1b, ushort_t* __restrict__ w2b,
                               ushort_t* __restrict__ w3b, ushort_t* __restrict__ sgb,
                               ushort_t* __restrict__ sub, ushort_t* __restrict__ sdb) {
  size_t chunk = (size_t)blockIdx.x * blockDim.x + threadIdx.x;
  if (chunk >= (size_t)NCONV_CHUNKS) return;
  size_t idx = chunk * 4;
  const float* src; ushort_t* dst;
  if (idx < (size_t)NBIG)                    { src = w1; dst = w1b; }
  else if (idx < 2ull * NBIG)                { src = w2; dst = w2b; idx -= (size_t)NBIG; }
  else if (idx < 3ull * NBIG)                { src = w3; dst = w3b; idx -= 2ull * NBIG; }
  else if (idx < 3ull * NBIG + NSML)         { src = sg; dst = sgb; idx -= 3ull * NBIG; }
  else if (idx < 3ull * NBIG + 2ull * NSML)  { src = su; dst = sub; idx -= 3ull * NBIG + NSML; }
  else                                       { src = sd; dst = sdb; idx -= 3ull * NBIG + 2ull * NSML; }
  f32x4 v = *(const f32x4*)&src[idx];
  short4v o;
  o[0] = (short)f2bf(v[0]); o[1] = (short)f2bf(v[1]);
  o[2] = (short)f2bf(v[2]); o[3] = (short)f2bf(v[3]);
  *(short4v*)&dst[idx] = o;
}

// ---------------- expert token lists ----------------
__global__ void build_lists(const float* __restrict__ ew, int* __restrict__ counts,
                            int* __restrict__ toklist) {
  int t = blockIdx.x * blockDim.x + threadIdx.x;
  if (t >= T_TOK) return;
#pragma unroll
  for (int e = 0; e < E_NUM; e++) {
    if (ew[t * E_NUM + e] > 0.f) {
      int p = atomicAdd(&counts[e], 1);
      toklist[e * T_TOK + p] = t;
    }
  }
}

__global__ void assign_kernel(const int* __restrict__ counts, int4* __restrict__ assign,
                              int* __restrict__ meta) {
  if (threadIdx.x != 0 || blockIdx.x != 0) return;
  int total = 0, base = 0;
  for (int e = 0; e < E_NUM; e++) {
    int c = counts[e];
    int nt = (c + BM - 1) / BM;
    for (int i = 0; i < nt; i++) {
      assign[total] = make_int4(e, i, base, c);
      total++;
    }
    base += nt * BM;
  }
  meta[0] = total;
}

// ---------------- shared experts: gate/up fused (SwiGLU) ----------------
__global__ __launch_bounds__(256, 2)
void shared_gemm1(const ushort_t* __restrict__ xb, const ushort_t* __restrict__ gwb,
                  const ushort_t* __restrict__ uwb, ushort_t* __restrict__ hout) {
  __shared__ short la[BM * LDT], lb1[BN * LDT], lb2[BN * LDT];
  int tid = threadIdx.x, wid = tid >> 6, lane = tid & 63;
  int m0 = blockIdx.x * BM, n0 = blockIdx.y * BN;
  int wm = (wid >> 1) << 6, wn = (wid & 1) << 6;
  f32x4 acc1[4][4] = {{{0.f}}}, acc2[4][4] = {{{0.f}}};
  for (int k0 = 0; k0 < D_DIM; k0 += BK) {
#pragma unroll
    for (int i = tid; i < BM * 4; i += 256) {
      int r = i >> 2, c = (i & 3) << 3;
      *(short8*)&la[r * LDT + c]  = *(const short8*)&xb[(size_t)(m0 + r) * D_DIM + k0 + c];
      *(short8*)&lb1[r * LDT + c] = *(const short8*)&gwb[(size_t)(n0 + r) * D_DIM + k0 + c];
      *(short8*)&lb2[r * LDT + c] = *(const short8*)&uwb[(size_t)(n0 + r) * D_DIM + k0 + c];
    }
    __syncthreads();
    int rsel = lane & 15, ksel = (lane >> 4) << 3;
    short8 af[4], bf1[4], bf2[4];
#pragma unroll
    for (int i = 0; i < 4; i++) {
      af[i]  = *(const short8*)&la[(wm + i * 16 + rsel) * LDT + ksel];
      bf1[i] = *(const short8*)&lb1[(wn + i * 16 + rsel) * LDT + ksel];
      bf2[i] = *(const short8*)&lb2[(wn + i * 16 + rsel) * LDT + ksel];
    }
#pragma unroll
    for (int mi = 0; mi < 4; mi++)
#pragma unroll
      for (int ni = 0; ni < 4; ni++) {
        acc1[mi][ni] = __builtin_amdgcn_mfma_f32_16x16x32_bf16(af[mi], bf1[ni], acc1[mi][ni], 0, 0, 0);
        acc2[mi][ni] = __builtin_amdgcn_mfma_f32_16x16x32_bf16(af[mi], bf2[ni], acc2[mi][ni], 0, 0, 0);
      }
    __syncthreads();
  }
  int cw = lane & 15, rw = (lane >> 4) << 2;
#pragma unroll
  for (int mi = 0; mi < 4; mi++)
#pragma unroll
    for (int ni = 0; ni < 4; ni++)
#pragma unroll
      for (int r = 0; r < 4; r++) {
        int row = m0 + wm + mi * 16 + rw + r;
        int col = n0 + wn + ni * 16 + cw;
        float g = acc1[mi][ni][r], u = acc2[mi][ni][r];
        float h = g * (1.f / (1.f + __expf(-g))) * u;
        hout[(size_t)row * SH_DIM + col] = f2bf(h);
      }
}

// ---------------- shared experts: down proj (writes d_out densely) ----------------
__global__ __launch_bounds__(256, 2)
void shared_gemm2(const ushort_t* __restrict__ hb, const ushort_t* __restrict__ dwb,
                  float* __restrict__ out) {
  __shared__ short la[BM * LDT], lb[BN * LDT];
  int tid = threadIdx.x, wid = tid >> 6, lane = tid & 63;
  int m0 = blockIdx.x * BM, n0 = blockIdx.y * BN;
  int wm = (wid >> 1) << 6, wn = (wid & 1) << 6;
  f32x4 acc[4][4] = {{{0.f}}};
  for (int k0 = 0; k0 < SH_DIM; k0 += BK) {
#pragma unroll
    for (int i = tid; i < BM * 4; i += 256) {
      int r = i >> 2, c = (i & 3) << 3;
      *(short8*)&la[r * LDT + c] = *(const short8*)&hb[(size_t)(m0 + r) * SH_DIM + k0 + c];
      *(short8*)&lb[r * LDT + c] = *(const short8*)&dwb[(size_t)(n0 + r) * SH_DIM + k0 + c];
    }
    __syncthreads();
    int rsel = lane & 15, ksel = (lane >> 4) << 3;
    short8 af[4], bf[4];
#pragma unroll
    for (int i = 0; i < 4; i++) {
      af[i] = *(const short8*)&la[(wm + i * 16 + rsel) * LDT + ksel];
      bf[i] = *(const short8*)&lb[(wn + i * 16 + rsel) * LDT + ksel];
    }
#pragma unroll
    for (int mi = 0; mi < 4; mi++)
#pragma unroll
      for (int ni = 0; ni < 4; ni++)
        acc[mi][ni] = __builtin_amdgcn_mfma_f32_16x16x32_bf16(af[mi], bf[ni], acc[mi][ni], 0, 0, 0);
    __syncthreads();
  }
  int cw = lane & 15, rw = (lane >> 4) << 2;
#pragma unroll
  for (int mi = 0; mi < 4; mi++)
#pragma unroll
    for (int ni = 0; ni < 4; ni++)
#pragma unroll
      for (int r = 0; r < 4; r++) {
        int row = m0 + wm + mi * 16 + rw + r;
        int col = n0 + wn + ni * 16 + cw;
        out[(size_t)row * D_DIM + col] = acc[mi][ni][r];
      }
}

// ---------------- routed experts: w1/w3 fused (SwiGLU), gathered A ----------------
__global__ __launch_bounds__(256, 2)
void routed_gemm1(const ushort_t* __restrict__ xb, const ushort_t* __restrict__ w1b,
                  const ushort_t* __restrict__ w3b, const int* __restrict__ toklist,
                  const int4* __restrict__ assign, const int* __restrict__ meta,
                  ushort_t* __restrict__ hbuf) {
  if ((int)blockIdx.x >= meta[0]) return;
  int4 as = assign[blockIdx.x];
  int e = as.x, tile = as.y, sbase = as.z, cnt = as.w;
  int n0 = blockIdx.y * BN;
  __shared__ short la[BM * LDT], lb1[BN * LDT], lb2[BN * LDT];
  __shared__ int ttok[BM];
  int tid = threadIdx.x, wid = tid >> 6, lane = tid & 63;
  if (tid < BM) {
    int idx = tile * BM + tid;
    ttok[tid] = (idx < cnt) ? toklist[e * T_TOK + idx] : -1;
  }
  __syncthreads();
  int wm = (wid >> 1) << 6, wn = (wid & 1) << 6;
  f32x4 acc1[4][4] = {{{0.f}}}, acc2[4][4] = {{{0.f}}};
  for (int k0 = 0; k0 < D_DIM; k0 += BK) {
#pragma unroll
    for (int i = tid; i < BM * 4; i += 256) {
      int r = i >> 2, c = (i & 3) << 3;
      int tk = ttok[r];
      short8 va = {};
      if (tk >= 0) va = *(const short8*)&xb[(size_t)tk * D_DIM + k0 + c];
      *(short8*)&la[r * LDT + c] = va;
      *(short8*)&lb1[r * LDT + c] = *(const short8*)&w1b[((size_t)e * F_DIM + n0 + r) * D_DIM + k0 + c];
      *(short8*)&lb2[r * LDT + c] = *(const short8*)&w3b[((size_t)e * F_DIM + n0 + r) * D_DIM + k0 + c];
    }
    __syncthreads();
    int rsel = lane & 15, ksel = (lane >> 4) << 3;
    short8 af[4], bf1[4], bf2[4];
#pragma unroll
    for (int i = 0; i < 4; i++) {
      af[i]  = *(const short8*)&la[(wm + i * 16 + rsel) * LDT + ksel];
      bf1[i] = *(const short8*)&lb1[(wn + i * 16 + rsel) * LDT + ksel];
      bf2[i] = *(const short8*)&lb2[(wn + i * 16 + rsel) * LDT + ksel];
    }
#pragma unroll
    for (int mi = 0; mi < 4; mi++)
#pragma unroll
      for (int ni = 0; ni < 4; ni++) {
        acc1[mi][ni] = __builtin_amdgcn_mfma_f32_16x16x32_bf16(af[mi], bf1[ni], acc1[mi][ni], 0, 0, 0);
        acc2[mi][ni] = __builtin_amdgcn_mfma_f32_16x16x32_bf16(af[mi], bf2[ni], acc2[mi][ni], 0, 0, 0);
      }
    __syncthreads();
  }
  int cw = lane & 15, rw = (lane >> 4) << 2;
#pragma unroll
  for (int mi = 0; mi < 4; mi++)
#pragma unroll
    for (int ni = 0; ni < 4; ni++)
#pragma unroll
      for (int r = 0; r < 4; r++) {
        int lrow = wm + mi * 16 + rw + r;
        int col = n0 + wn + ni * 16 + cw;
        float g = acc1[mi][ni][r], u = acc2[mi][ni][r];
        float h = g * (1.f / (1.f + __expf(-g))) * u;
        hbuf[(size_t)(sbase + tile * BM + lrow) * F_DIM + col] = f2bf(h);
      }
}

// ---------------- routed experts: down proj, scaled atomic scatter ----------------
__global__ __launch_bounds__(256, 2)
void routed_gemm2(const ushort_t* __restrict__ hbuf, const ushort_t* __restrict__ w2b,
                  const int* __restrict__ toklist, const float* __restrict__ ew,
                  const int4* __restrict__ assign, const int* __restrict__ meta,
                  float* __restrict__ out) {
  if ((int)blockIdx.x >= meta[0]) return;
  int4 as = assign[blockIdx.x];
  int e = as.x, tile = as.y, sbase = as.z, cnt = as.w;
  int n0 = blockIdx.y * BN;
  __shared__ short la[BM * LDT], lb[BN * LDT];
  __shared__ int ttok[BM];
  __shared__ float twt[BM];
  int tid = threadIdx.x, wid = tid >> 6, lane = tid & 63;
  if (tid < BM) {
    int idx = tile * BM + tid;
    int tk = (idx < cnt) ? toklist[e * T_TOK + idx] : -1;
    ttok[tid] = tk;
    twt[tid] = (tk >= 0) ? ew[tk * E_NUM + e] : 0.f;
  }
  __syncthreads();
  int wm = (wid >> 1) << 6, wn = (wid & 1) << 6;
  f32x4 acc[4][4] = {{{0.f}}};
  for (int k0 = 0; k0 < F_DIM; k0 += BK) {
#pragma unroll
    for (int i = tid; i < BM * 4; i += 256) {
      int r = i >> 2, c = (i & 3) << 3;
      *(short8*)&la[r * LDT + c] = *(const short8*)&hbuf[(size_t)(sbase + tile * BM + r) * F_DIM + k0 + c];
      *(short8*)&lb[r * LDT + c] = *(const short8*)&w2b[((size_t)e * D_DIM + n0 + r) * F_DIM + k0 + c];
    }
    __syncthreads();
    int rsel = lane & 15, ksel = (lane >> 4) << 3;
    short8 af[4], bf[4];
#pragma unroll
    for (int i = 0; i < 4; i++) {
      af[i] = *(const short8*)&la[(wm + i * 16 + rsel) * LDT + ksel];
      bf[i] = *(const short8*)&lb[(wn + i * 16 + rsel) * LDT + ksel];
    }
#pragma unroll
    for (int mi = 0; mi < 4; mi++)
#pragma unroll
      for (int ni = 0; ni < 4; ni++)
        acc[mi][ni] = __builtin_amdgcn_mfma_f32_16x16x32_bf16(af[mi], bf[ni], acc[mi][ni], 0, 0, 0);
    __syncthreads();
  }
  int cw = lane & 15, rw = (lane >> 4) << 2;
#pragma unroll
  for (int mi = 0; mi < 4; mi++)
#pragma unroll
    for (int ni = 0; ni < 4; ni++)
#pragma unroll
      for (int r = 0; r < 4; r++) {
        int lrow = wm + mi * 16 + rw + r;
        int tk = ttok[lrow];
        if (tk >= 0) {
          int col = n0 + wn + ni * 16 + cw;
          atomicAdd(&out[(size_t)tk * D_DIM + col], twt[lrow] * acc[mi][ni][r]);
        }
      }
}

extern "C" void kernel_launch(void* const* d_in, const int* in_sizes, int n_in,
                              void* d_out, int out_size, void* d_ws, size_t ws_size,
                              hipStream_t stream) {
  const float* x  = (const float*)d_in[0];
  const float* gw = (const float*)d_in[1];
  const float* gb = (const float*)d_in[2];
  const float* w1 = (const float*)d_in[3];
  const float* w2 = (const float*)d_in[4];
  const float* w3 = (const float*)d_in[5];
  const float* sg = (const float*)d_in[6];
  const float* su = (const float*)d_in[7];
  const float* sd = (const float*)d_in[8];
  float* out = (float*)d_out;

  char* ws = (char*)d_ws;
  size_t off = 0;
  auto alloc = [&](size_t bytes) {
    char* p = ws + off;
    off += (bytes + 255) & ~(size_t)255;
    return p;
  };
  ushort_t* xb   = (ushort_t*)alloc((size_t)T_TOK * D_DIM * 2);
  ushort_t* w1b  = (ushort_t*)alloc((size_t)NBIG * 2);
  ushort_t* w2b  = (ushort_t*)alloc((size_t)NBIG * 2);
  ushort_t* w3b  = (ushort_t*)alloc((size_t)NBIG * 2);
  ushort_t* sgb  = (ushort_t*)alloc((size_t)NSML * 2);
  ushort_t* sub  = (ushort_t*)alloc((size_t)NSML * 2);
  ushort_t* sdb  = (ushort_t*)alloc((size_t)NSML * 2);
  float*    ew   = (float*)alloc((size_t)T_TOK * E_NUM * 4);
  ushort_t* hsh  = (ushort_t*)alloc((size_t)T_TOK * SH_DIM * 2);
  ushort_t* hbuf = (ushort_t*)alloc((size_t)MAX_TILES * BM * F_DIM * 2);
  int*      toklist = (int*)alloc((size_t)E_NUM * T_TOK * 4);
  int*      counts  = (int*)alloc(64);
  int4*     assign  = (int4*)alloc((MAX_TILES + 8) * sizeof(int4));
  int*      meta    = (int*)alloc(64);

  hipMemsetAsync(counts, 0, 64, stream);
  gate_kernel<<<T_TOK, 64, 0, stream>>>(x, gw, gb, ew, xb);
  convert_kernel<<<NCONV_CHUNKS / 256, 256, 0, stream>>>(w1, w2, w3, sg, su, sd,
                                                         w1b, w2b, w3b, sgb, sub, sdb);
  build_lists<<<(T_TOK + 255) / 256, 256, 0, stream>>>(ew, counts, toklist);
  assign_kernel<<<1, 64, 0, stream>>>(counts, assign, meta);
  shared_gemm1<<<dim3(T_TOK / BM, SH_DIM / BN), 256, 0, stream>>>(xb, sgb, sub, hsh);
  shared_gemm2<<<dim3(T_TOK / BM, D_DIM / BN), 256, 0, stream>>>(hsh, sdb, out);
  routed_gemm1<<<dim3(MAX_TILES, F_DIM / BN), 256, 0, stream>>>(xb, w1b, w3b, toklist,
                                                                assign, meta, hbuf);
  routed_gemm2<<<dim3(MAX_TILES, D_DIM / BN), 256, 0, stream>>>(hbuf, w2b, toklist, ew,
                                                                assign, meta, out);
}

// Round 7
// 300.482 us; speedup vs baseline: 1.0343x; 1.0343x over previous
//
#include <hip/hip_runtime.h>
#include <hip/hip_bf16.h>
#include <stdint.h>

#define T_TOK 4096
#define D_DIM 1024
#define E_NUM 8
#define F_DIM 512
#define SH_DIM 1024
#define SCALE_F 2.5f

#define BM 128
#define BN 128
#define BK 32
#define LDT 40   // padded LDS row stride (bf16 elems)

#define NBIG (E_NUM * F_DIM * D_DIM)   // 4194304
#define NSML (SH_DIM * D_DIM)          // 1048576
#define NCONV_CHUNKS ((3 * NBIG + 3 * NSML) / 4)  // 3932160
#define MAX_TILES 72

// grid split points
#define UP_SHARED_BLOCKS 256                    // 32 m-tiles x 8 n-chunks (SH=1024)
#define UP_TOTAL (UP_SHARED_BLOCKS + MAX_TILES * 4)   // routed: 72 x (512/128)
#define DN_SHARED_BLOCKS 256                    // 32 m-tiles x 8 n-chunks (D=1024)
#define DN_TOTAL (DN_SHARED_BLOCKS + MAX_TILES * 8)   // routed: 72 x (1024/128)

typedef unsigned short ushort_t;
typedef __attribute__((ext_vector_type(8))) short short8;
typedef __attribute__((ext_vector_type(4))) short short4v;
typedef __attribute__((ext_vector_type(4))) float f32x4;

__device__ inline ushort_t f2bf(float f) {
  union { float f; unsigned u; } cv; cv.f = f;
  unsigned u = cv.u;
  unsigned r = (u + 0x7FFFu + ((u >> 16) & 1u)) >> 16;  // RNE
  return (ushort_t)r;
}

// ---------------- gate (f32 exact) + x -> bf16 ----------------
__global__ void gate_kernel(const float* __restrict__ x, const float* __restrict__ gw,
                            const float* __restrict__ gb, float* __restrict__ ew,
                            ushort_t* __restrict__ xb) {
  int t = blockIdx.x;
  int lane = threadIdx.x;  // 64 threads
  const float* xr = x + (size_t)t * D_DIM;
  float xv[16];
#pragma unroll
  for (int i = 0; i < 16; i++) xv[i] = xr[lane + (i << 6)];
#pragma unroll
  for (int i = 0; i < 16; i++) xb[(size_t)t * D_DIM + lane + (i << 6)] = f2bf(xv[i]);
  float logit[E_NUM];
#pragma unroll
  for (int e = 0; e < E_NUM; e++) {
    const float* wr = gw + (size_t)e * D_DIM;
    float s = 0.f;
#pragma unroll
    for (int i = 0; i < 16; i++) s += xv[i] * wr[lane + (i << 6)];
#pragma unroll
    for (int off = 32; off; off >>= 1) s += __shfl_xor(s, off, 64);
    logit[e] = s;
  }
  if (lane == 0) {
    float scores[E_NUM], sc[E_NUM];
#pragma unroll
    for (int e = 0; e < E_NUM; e++) {
      scores[e] = 1.f / (1.f + expf(-logit[e]));
      sc[e] = scores[e] + gb[e];
    }
    float gs[4];
#pragma unroll
    for (int g = 0; g < 4; g++) gs[g] = sc[2 * g] + sc[2 * g + 1];
    int g0 = 0;
#pragma unroll
    for (int g = 1; g < 4; g++) if (gs[g] > gs[g0]) g0 = g;
    int g1 = -1;
#pragma unroll
    for (int g = 0; g < 4; g++) { if (g == g0) continue; if (g1 < 0 || gs[g] > gs[g1]) g1 = g; }
    float tmp[E_NUM];
#pragma unroll
    for (int e = 0; e < E_NUM; e++) {
      int g = e >> 1;
      tmp[e] = (g == g0 || g == g1) ? sc[e] : 0.f;
    }
    int e0 = 0;
#pragma unroll
    for (int e = 1; e < E_NUM; e++) if (tmp[e] > tmp[e0]) e0 = e;
    int e1 = -1;
#pragma unroll
    for (int e = 0; e < E_NUM; e++) { if (e == e0) continue; if (e1 < 0 || tmp[e] > tmp[e1]) e1 = e; }
    float w0 = scores[e0], w1v = scores[e1];
    float inv = SCALE_F / (w0 + w1v + 1e-20f);
    float o[E_NUM];
#pragma unroll
    for (int e = 0; e < E_NUM; e++) o[e] = 0.f;
    o[e0] = w0 * inv;
    o[e1] = w1v * inv;
#pragma unroll
    for (int e = 0; e < E_NUM; e++) ew[t * E_NUM + e] = o[e];
  }
}

// ---------------- weight f32 -> bf16 conversion ----------------
__global__ void convert_kernel(const float* __restrict__ w1, const float* __restrict__ w2,
                               const float* __restrict__ w3, const float* __restrict__ sg,
                               const float* __restrict__ su, const float* __restrict__ sd,
                               ushort_t* __restrict__ w1b, ushort_t* __restrict__ w2b,
                               ushort_t* __restrict__ w3b, ushort_t* __restrict__ sgb,
                               ushort_t* __restrict__ sub, ushort_t* __restrict__ sdb) {
  size_t chunk = (size_t)blockIdx.x * blockDim.x + threadIdx.x;
  if (chunk >= (size_t)NCONV_CHUNKS) return;
  size_t idx = chunk * 4;
  const float* src; ushort_t* dst;
  if (idx < (size_t)NBIG)                    { src = w1; dst = w1b; }
  else if (idx < 2ull * NBIG)                { src = w2; dst = w2b; idx -= (size_t)NBIG; }
  else if (idx < 3ull * NBIG)                { src = w3; dst = w3b; idx -= 2ull * NBIG; }
  else if (idx < 3ull * NBIG + NSML)         { src = sg; dst = sgb; idx -= 3ull * NBIG; }
  else if (idx < 3ull * NBIG + 2ull * NSML)  { src = su; dst = sub; idx -= 3ull * NBIG + NSML; }
  else                                       { src = sd; dst = sdb; idx -= 3ull * NBIG + 2ull * NSML; }
  f32x4 v = *(const f32x4*)&src[idx];
  short4v o;
  o[0] = (short)f2bf(v[0]); o[1] = (short)f2bf(v[1]);
  o[2] = (short)f2bf(v[2]); o[3] = (short)f2bf(v[3]);
  *(short4v*)&dst[idx] = o;
}

// ---------------- expert token lists ----------------
__global__ void build_lists(const float* __restrict__ ew, int* __restrict__ counts,
                            int* __restrict__ toklist) {
  int t = blockIdx.x * blockDim.x + threadIdx.x;
  if (t >= T_TOK) return;
#pragma unroll
  for (int e = 0; e < E_NUM; e++) {
    if (ew[t * E_NUM + e] > 0.f) {
      int p = atomicAdd(&counts[e], 1);
      toklist[e * T_TOK + p] = t;
    }
  }
}

__global__ void assign_kernel(const int* __restrict__ counts, int4* __restrict__ assign,
                              int* __restrict__ meta) {
  if (threadIdx.x != 0 || blockIdx.x != 0) return;
  int total = 0, base = 0;
  for (int e = 0; e < E_NUM; e++) {
    int c = counts[e];
    int nt = (c + BM - 1) / BM;
    for (int i = 0; i < nt; i++) {
      assign[total] = make_int4(e, i, base, c);
      total++;
    }
    base += nt * BM;
  }
  meta[0] = total;
}

// ---------------- fused up-proj: shared gate/up + routed w1/w3 (SwiGLU) ----------------
// grid.x = UP_TOTAL; blocks [0,256): shared path; [256,...): routed path.
// Both paths: A rows gathered from xb via ttok, B rows have K-stride D_DIM, K = D_DIM.
__global__ __launch_bounds__(256, 2)
void up_gemm(const ushort_t* __restrict__ xb,
             const ushort_t* __restrict__ sgb, const ushort_t* __restrict__ sub,
             const ushort_t* __restrict__ w1b, const ushort_t* __restrict__ w3b,
             const int* __restrict__ toklist,
             const int4* __restrict__ assign, const int* __restrict__ meta,
             ushort_t* __restrict__ hsh, ushort_t* __restrict__ hbuf) {
  __shared__ short la[BM * LDT], lb1[BN * LDT], lb2[BN * LDT];
  __shared__ int ttok[BM];
  int bid = blockIdx.x;
  int tid = threadIdx.x, wid = tid >> 6, lane = tid & 63;

  const ushort_t *b1base, *b2base;
  ushort_t* dst;
  int n0, dstride;
  size_t rowbase;

  if (bid < UP_SHARED_BLOCKS) {
    int m0 = (bid >> 3) * BM;
    n0 = (bid & 7) * BN;
    b1base = sgb + (size_t)n0 * D_DIM;
    b2base = sub + (size_t)n0 * D_DIM;
    dst = hsh; dstride = SH_DIM; rowbase = m0;
    if (tid < BM) ttok[tid] = m0 + tid;
  } else {
    int rid = bid - UP_SHARED_BLOCKS;
    int tidx = rid >> 2;
    if (tidx >= meta[0]) return;
    int4 as = assign[tidx];
    int e = as.x, tile = as.y, sbase = as.z, cnt = as.w;
    n0 = (rid & 3) * BN;
    b1base = w1b + ((size_t)e * F_DIM + n0) * D_DIM;
    b2base = w3b + ((size_t)e * F_DIM + n0) * D_DIM;
    dst = hbuf; dstride = F_DIM; rowbase = (size_t)sbase + (size_t)tile * BM;
    if (tid < BM) {
      int idx = tile * BM + tid;
      ttok[tid] = (idx < cnt) ? toklist[e * T_TOK + idx] : -1;
    }
  }
  __syncthreads();

  int wm = (wid >> 1) << 6, wn = (wid & 1) << 6;
  f32x4 acc1[4][4] = {{{0.f}}}, acc2[4][4] = {{{0.f}}};
  for (int k0 = 0; k0 < D_DIM; k0 += BK) {
#pragma unroll
    for (int i = tid; i < BM * 4; i += 256) {
      int r = i >> 2, c = (i & 3) << 3;
      int tk = ttok[r];
      short8 va = {};
      if (tk >= 0) va = *(const short8*)&xb[(size_t)tk * D_DIM + k0 + c];
      *(short8*)&la[r * LDT + c]  = va;
      *(short8*)&lb1[r * LDT + c] = *(const short8*)&b1base[(size_t)r * D_DIM + k0 + c];
      *(short8*)&lb2[r * LDT + c] = *(const short8*)&b2base[(size_t)r * D_DIM + k0 + c];
    }
    __syncthreads();
    int rsel = lane & 15, ksel = (lane >> 4) << 3;
    short8 af[4], bf1[4], bf2[4];
#pragma unroll
    for (int i = 0; i < 4; i++) {
      af[i]  = *(const short8*)&la[(wm + i * 16 + rsel) * LDT + ksel];
      bf1[i] = *(const short8*)&lb1[(wn + i * 16 + rsel) * LDT + ksel];
      bf2[i] = *(const short8*)&lb2[(wn + i * 16 + rsel) * LDT + ksel];
    }
#pragma unroll
    for (int mi = 0; mi < 4; mi++)
#pragma unroll
      for (int ni = 0; ni < 4; ni++) {
        acc1[mi][ni] = __builtin_amdgcn_mfma_f32_16x16x32_bf16(af[mi], bf1[ni], acc1[mi][ni], 0, 0, 0);
        acc2[mi][ni] = __builtin_amdgcn_mfma_f32_16x16x32_bf16(af[mi], bf2[ni], acc2[mi][ni], 0, 0, 0);
      }
    __syncthreads();
  }
  int cw = lane & 15, rw = (lane >> 4) << 2;
#pragma unroll
  for (int mi = 0; mi < 4; mi++)
#pragma unroll
    for (int ni = 0; ni < 4; ni++)
#pragma unroll
      for (int r = 0; r < 4; r++) {
        int lrow = wm + mi * 16 + rw + r;
        int col = n0 + wn + ni * 16 + cw;
        float g = acc1[mi][ni][r], u = acc2[mi][ni][r];
        float h = g * (1.f / (1.f + __expf(-g))) * u;
        dst[(rowbase + lrow) * (size_t)dstride + col] = f2bf(h);
      }
}

// ---------------- fused down-proj: shared down + routed w2, all atomicAdd ----------------
// d_out must be zeroed beforehand. grid.x = DN_TOTAL.
__global__ __launch_bounds__(256, 2)
void down_gemm(const ushort_t* __restrict__ hsh, const ushort_t* __restrict__ hbuf,
               const ushort_t* __restrict__ sdb, const ushort_t* __restrict__ w2b,
               const int* __restrict__ toklist, const float* __restrict__ ew,
               const int4* __restrict__ assign, const int* __restrict__ meta,
               float* __restrict__ out) {
  __shared__ short la[BM * LDT], lb[BN * LDT];
  __shared__ int ttok[BM];
  __shared__ float twt[BM];
  int bid = blockIdx.x;
  int tid = threadIdx.x, wid = tid >> 6, lane = tid & 63;

  const ushort_t *abase, *bbase;
  int n0, kend;

  if (bid < DN_SHARED_BLOCKS) {
    int m0 = (bid >> 3) * BM;
    n0 = (bid & 7) * BN;
    abase = hsh + (size_t)m0 * SH_DIM;
    bbase = sdb + (size_t)n0 * SH_DIM;
    kend = SH_DIM;
    if (tid < BM) { ttok[tid] = m0 + tid; twt[tid] = 1.f; }
  } else {
    int rid = bid - DN_SHARED_BLOCKS;
    int tidx = rid >> 3;
    if (tidx >= meta[0]) return;
    int4 as = assign[tidx];
    int e = as.x, tile = as.y, sbase = as.z, cnt = as.w;
    n0 = (rid & 7) * BN;
    abase = hbuf + ((size_t)sbase + (size_t)tile * BM) * F_DIM;
    bbase = w2b + ((size_t)e * D_DIM + n0) * F_DIM;
    kend = F_DIM;
    if (tid < BM) {
      int idx = tile * BM + tid;
      int tk = (idx < cnt) ? toklist[e * T_TOK + idx] : -1;
      ttok[tid] = tk;
      twt[tid] = (tk >= 0) ? ew[tk * E_NUM + e] : 0.f;
    }
  }
  __syncthreads();

  int wm = (wid >> 1) << 6, wn = (wid & 1) << 6;
  f32x4 acc[4][4] = {{{0.f}}};
  for (int k0 = 0; k0 < kend; k0 += BK) {
#pragma unroll
    for (int i = tid; i < BM * 4; i += 256) {
      int r = i >> 2, c = (i & 3) << 3;
      *(short8*)&la[r * LDT + c] = *(const short8*)&abase[(size_t)r * kend + k0 + c];
      *(short8*)&lb[r * LDT + c] = *(const short8*)&bbase[(size_t)r * kend + k0 + c];
    }
    __syncthreads();
    int rsel = lane & 15, ksel = (lane >> 4) << 3;
    short8 af[4], bf[4];
#pragma unroll
    for (int i = 0; i < 4; i++) {
      af[i] = *(const short8*)&la[(wm + i * 16 + rsel) * LDT + ksel];
      bf[i] = *(const short8*)&lb[(wn + i * 16 + rsel) * LDT + ksel];
    }
#pragma unroll
    for (int mi = 0; mi < 4; mi++)
#pragma unroll
      for (int ni = 0; ni < 4; ni++)
        acc[mi][ni] = __builtin_amdgcn_mfma_f32_16x16x32_bf16(af[mi], bf[ni], acc[mi][ni], 0, 0, 0);
    __syncthreads();
  }
  int cw = lane & 15, rw = (lane >> 4) << 2;
#pragma unroll
  for (int mi = 0; mi < 4; mi++)
#pragma unroll
    for (int ni = 0; ni < 4; ni++)
#pragma unroll
      for (int r = 0; r < 4; r++) {
        int lrow = wm + mi * 16 + rw + r;
        int tk = ttok[lrow];
        if (tk >= 0) {
          int col = n0 + wn + ni * 16 + cw;
          atomicAdd(&out[(size_t)tk * D_DIM + col], twt[lrow] * acc[mi][ni][r]);
        }
      }
}

extern "C" void kernel_launch(void* const* d_in, const int* in_sizes, int n_in,
                              void* d_out, int out_size, void* d_ws, size_t ws_size,
                              hipStream_t stream) {
  const float* x  = (const float*)d_in[0];
  const float* gw = (const float*)d_in[1];
  const float* gb = (const float*)d_in[2];
  const float* w1 = (const float*)d_in[3];
  const float* w2 = (const float*)d_in[4];
  const float* w3 = (const float*)d_in[5];
  const float* sg = (const float*)d_in[6];
  const float* su = (const float*)d_in[7];
  const float* sd = (const float*)d_in[8];
  float* out = (float*)d_out;

  char* ws = (char*)d_ws;
  size_t off = 0;
  auto alloc = [&](size_t bytes) {
    char* p = ws + off;
    off += (bytes + 255) & ~(size_t)255;
    return p;
  };
  ushort_t* xb   = (ushort_t*)alloc((size_t)T_TOK * D_DIM * 2);
  ushort_t* w1b  = (ushort_t*)alloc((size_t)NBIG * 2);
  ushort_t* w2b  = (ushort_t*)alloc((size_t)NBIG * 2);
  ushort_t* w3b  = (ushort_t*)alloc((size_t)NBIG * 2);
  ushort_t* sgb  = (ushort_t*)alloc((size_t)NSML * 2);
  ushort_t* sub  = (ushort_t*)alloc((size_t)NSML * 2);
  ushort_t* sdb  = (ushort_t*)alloc((size_t)NSML * 2);
  float*    ew   = (float*)alloc((size_t)T_TOK * E_NUM * 4);
  ushort_t* hsh  = (ushort_t*)alloc((size_t)T_TOK * SH_DIM * 2);
  ushort_t* hbuf = (ushort_t*)alloc((size_t)MAX_TILES * BM * F_DIM * 2);
  int*      toklist = (int*)alloc((size_t)E_NUM * T_TOK * 4);
  int*      counts  = (int*)alloc(64);
  int4*     assign  = (int4*)alloc((MAX_TILES + 8) * sizeof(int4));
  int*      meta    = (int*)alloc(64);

  hipMemsetAsync(counts, 0, 64, stream);
  hipMemsetAsync(out, 0, (size_t)out_size * sizeof(float), stream);
  gate_kernel<<<T_TOK, 64, 0, stream>>>(x, gw, gb, ew, xb);
  convert_kernel<<<NCONV_CHUNKS / 256, 256, 0, stream>>>(w1, w2, w3, sg, su, sd,
                                                         w1b, w2b, w3b, sgb, sub, sdb);
  build_lists<<<(T_TOK + 255) / 256, 256, 0, stream>>>(ew, counts, toklist);
  assign_kernel<<<1, 64, 0, stream>>>(counts, assign, meta);
  up_gemm<<<UP_TOTAL, 256, 0, stream>>>(xb, sgb, sub, w1b, w3b, toklist, assign, meta,
                                        hsh, hbuf);
  down_gemm<<<DN_TOTAL, 256, 0, stream>>>(hsh, hbuf, sdb, w2b, toklist, ew, assign, meta,
                                          out);
}

// Round 10
// 276.741 us; speedup vs baseline: 1.1230x; 1.0858x over previous
//
#include <hip/hip_runtime.h>
#include <hip/hip_bf16.h>
#include <stdint.h>

#define T_TOK 4096
#define D_DIM 1024
#define E_NUM 8
#define F_DIM 512
#define SH_DIM 1024
#define SCALE_F 2.5f

#define BM 128
#define BN 128
#define BK 32

#define NBIG (E_NUM * F_DIM * D_DIM)   // 4194304
#define NSML (SH_DIM * D_DIM)          // 1048576
#define NCONV_CHUNKS ((3 * NBIG + 3 * NSML) / 4)  // 3932160
#define MAX_TILES 72

// grid split points
#define UP_SHARED_BLOCKS 256                    // 32 m-tiles x 8 n-chunks (SH=1024)
#define UP_TOTAL (UP_SHARED_BLOCKS + MAX_TILES * 4)   // routed: 72 x (512/128)
#define DN_SHARED_BLOCKS 256                    // 32 m-tiles x 8 n-chunks (D=1024)
#define DN_TOTAL (DN_SHARED_BLOCKS + MAX_TILES * 8)   // routed: 72 x (1024/128)

typedef unsigned short ushort_t;
typedef __attribute__((ext_vector_type(8))) short short8;
typedef __attribute__((ext_vector_type(4))) short short4v;
typedef __attribute__((ext_vector_type(4))) float f32x4;

// global_load_lds, 16B per lane: LDS dest = uniform base + lane*16 (linear).
#define GLL16(g, l)                                                                  \
  __builtin_amdgcn_global_load_lds(                                                  \
      (const __attribute__((address_space(1))) void*)(g),                            \
      (__attribute__((address_space(3))) void*)(l), 16, 0, 0)

__device__ inline ushort_t f2bf(float f) {
  union { float f; unsigned u; } cv; cv.f = f;
  unsigned u = cv.u;
  unsigned r = (u + 0x7FFFu + ((u >> 16) & 1u)) >> 16;  // RNE
  return (ushort_t)r;
}

// ---------------- gate (f32 exact) + x -> bf16 ----------------
__global__ void gate_kernel(const float* __restrict__ x, const float* __restrict__ gw,
                            const float* __restrict__ gb, float* __restrict__ ew,
                            ushort_t* __restrict__ xb) {
  int t = blockIdx.x;
  int lane = threadIdx.x;  // 64 threads
  const float* xr = x + (size_t)t * D_DIM;
  float xv[16];
#pragma unroll
  for (int i = 0; i < 16; i++) xv[i] = xr[lane + (i << 6)];
#pragma unroll
  for (int i = 0; i < 16; i++) xb[(size_t)t * D_DIM + lane + (i << 6)] = f2bf(xv[i]);
  float logit[E_NUM];
#pragma unroll
  for (int e = 0; e < E_NUM; e++) {
    const float* wr = gw + (size_t)e * D_DIM;
    float s = 0.f;
#pragma unroll
    for (int i = 0; i < 16; i++) s += xv[i] * wr[lane + (i << 6)];
#pragma unroll
    for (int off = 32; off; off >>= 1) s += __shfl_xor(s, off, 64);
    logit[e] = s;
  }
  if (lane == 0) {
    float scores[E_NUM], sc[E_NUM];
#pragma unroll
    for (int e = 0; e < E_NUM; e++) {
      scores[e] = 1.f / (1.f + expf(-logit[e]));
      sc[e] = scores[e] + gb[e];
    }
    float gs[4];
#pragma unroll
    for (int g = 0; g < 4; g++) gs[g] = sc[2 * g] + sc[2 * g + 1];
    int g0 = 0;
#pragma unroll
    for (int g = 1; g < 4; g++) if (gs[g] > gs[g0]) g0 = g;
    int g1 = -1;
#pragma unroll
    for (int g = 0; g < 4; g++) { if (g == g0) continue; if (g1 < 0 || gs[g] > gs[g1]) g1 = g; }
    float tmp[E_NUM];
#pragma unroll
    for (int e = 0; e < E_NUM; e++) {
      int g = e >> 1;
      tmp[e] = (g == g0 || g == g1) ? sc[e] : 0.f;
    }
    int e0 = 0;
#pragma unroll
    for (int e = 1; e < E_NUM; e++) if (tmp[e] > tmp[e0]) e0 = e;
    int e1 = -1;
#pragma unroll
    for (int e = 0; e < E_NUM; e++) { if (e == e0) continue; if (e1 < 0 || tmp[e] > tmp[e1]) e1 = e; }
    float w0 = scores[e0], w1v = scores[e1];
    float inv = SCALE_F / (w0 + w1v + 1e-20f);
    float o[E_NUM];
#pragma unroll
    for (int e = 0; e < E_NUM; e++) o[e] = 0.f;
    o[e0] = w0 * inv;
    o[e1] = w1v * inv;
#pragma unroll
    for (int e = 0; e < E_NUM; e++) ew[t * E_NUM + e] = o[e];
  }
}

// ---------------- weight f32 -> bf16 conversion ----------------
__global__ void convert_kernel(const float* __restrict__ w1, const float* __restrict__ w2,
                               const float* __restrict__ w3, const float* __restrict__ sg,
                               const float* __restrict__ su, const float* __restrict__ sd,
                               ushort_t* __restrict__ w1b, ushort_t* __restrict__ w2b,
                               ushort_t* __restrict__ w3b, ushort_t* __restrict__ sgb,
                               ushort_t* __restrict__ sub, ushort_t* __restrict__ sdb) {
  size_t chunk = (size_t)blockIdx.x * blockDim.x + threadIdx.x;
  if (chunk >= (size_t)NCONV_CHUNKS) return;
  size_t idx = chunk * 4;
  const float* src; ushort_t* dst;
  if (idx < (size_t)NBIG)                    { src = w1; dst = w1b; }
  else if (idx < 2ull * NBIG)                { src = w2; dst = w2b; idx -= (size_t)NBIG; }
  else if (idx < 3ull * NBIG)                { src = w3; dst = w3b; idx -= 2ull * NBIG; }
  else if (idx < 3ull * NBIG + NSML)         { src = sg; dst = sgb; idx -= 3ull * NBIG; }
  else if (idx < 3ull * NBIG + 2ull * NSML)  { src = su; dst = sub; idx -= 3ull * NBIG + NSML; }
  else                                       { src = sd; dst = sdb; idx -= 3ull * NBIG + 2ull * NSML; }
  f32x4 v = *(const f32x4*)&src[idx];
  short4v o;
  o[0] = (short)f2bf(v[0]); o[1] = (short)f2bf(v[1]);
  o[2] = (short)f2bf(v[2]); o[3] = (short)f2bf(v[3]);
  *(short4v*)&dst[idx] = o;
}

// ---------------- expert token lists ----------------
__global__ void build_lists(const float* __restrict__ ew, int* __restrict__ counts,
                            int* __restrict__ toklist) {
  int t = blockIdx.x * blockDim.x + threadIdx.x;
  if (t >= T_TOK) return;
#pragma unroll
  for (int e = 0; e < E_NUM; e++) {
    if (ew[t * E_NUM + e] > 0.f) {
      int p = atomicAdd(&counts[e], 1);
      toklist[e * T_TOK + p] = t;
    }
  }
}

__global__ void assign_kernel(const int* __restrict__ counts, int4* __restrict__ assign,
                              int* __restrict__ meta) {
  if (threadIdx.x != 0 || blockIdx.x != 0) return;
  int total = 0, base = 0;
  for (int e = 0; e < E_NUM; e++) {
    int c = counts[e];
    int nt = (c + BM - 1) / BM;
    for (int i = 0; i < nt; i++) {
      assign[total] = make_int4(e, i, base, c);
      total++;
    }
    base += nt * BM;
  }
  meta[0] = total;
}

// ---------------- fused up-proj: gll staging + swizzled LDS ----------------
// LDS tiles are linear [128][32] bf16 (64 B rows). Swizzle: 16B-chunk index
// c16' = c16 ^ ((row>>1)&3), applied to the GLOBAL source at stage time and
// to the ds_read address; gll writes linearly (base + lane*16).
__global__ __launch_bounds__(256, 2)
void up_gemm(const ushort_t* __restrict__ xb,
             const ushort_t* __restrict__ sgb, const ushort_t* __restrict__ sub,
             const ushort_t* __restrict__ w1b, const ushort_t* __restrict__ w3b,
             const int* __restrict__ toklist,
             const int4* __restrict__ assign, const int* __restrict__ meta,
             ushort_t* __restrict__ hsh, ushort_t* __restrict__ hbuf) {
  __shared__ ushort_t la[BM * BK], lb1[BN * BK], lb2[BN * BK];
  __shared__ int ttok[BM];
  int bid = blockIdx.x;
  int tid = threadIdx.x, wid = tid >> 6, lane = tid & 63;

  const ushort_t *b1base, *b2base;
  ushort_t* dst;
  int n0, dstride;
  size_t rowbase;

  if (bid < UP_SHARED_BLOCKS) {
    int m0 = (bid >> 3) * BM;
    n0 = (bid & 7) * BN;
    b1base = sgb + (size_t)n0 * D_DIM;
    b2base = sub + (size_t)n0 * D_DIM;
    dst = hsh; dstride = SH_DIM; rowbase = m0;
    if (tid < BM) ttok[tid] = m0 + tid;
  } else {
    int rid = bid - UP_SHARED_BLOCKS;
    int tidx = rid >> 2;
    if (tidx >= meta[0]) return;
    int4 as = assign[tidx];
    int e = as.x, tile = as.y, sbase = as.z, cnt = as.w;
    n0 = (rid & 3) * BN;
    b1base = w1b + ((size_t)e * F_DIM + n0) * D_DIM;
    b2base = w3b + ((size_t)e * F_DIM + n0) * D_DIM;
    dst = hbuf; dstride = F_DIM; rowbase = (size_t)sbase + (size_t)tile * BM;
    if (tid < BM) {
      int idx = tile * BM + tid;
      ttok[tid] = (idx < cnt) ? toklist[e * T_TOK + idx] : -1;
    }
  }
  __syncthreads();

  // --- fixed per-lane staging geometry (rows srow, srow+16; chunk c16) ---
  int srow = (wid << 5) + (lane >> 2);
  int c16 = lane & 3;
  int s0 = c16 ^ ((srow >> 1) & 3);
  int s1 = c16 ^ (((srow + 16) >> 1) & 3);
  int tka = ttok[srow], tkb = ttok[srow + 16];
  const ushort_t* gA0 = xb + (size_t)(tka < 0 ? 0 : tka) * D_DIM + (s0 << 3);
  const ushort_t* gA1 = xb + (size_t)(tkb < 0 ? 0 : tkb) * D_DIM + (s1 << 3);
  const ushort_t* gB1a = b1base + (size_t)srow * D_DIM + (s0 << 3);
  const ushort_t* gB1b = b1base + (size_t)(srow + 16) * D_DIM + (s1 << 3);
  const ushort_t* gB2a = b2base + (size_t)srow * D_DIM + (s0 << 3);
  const ushort_t* gB2b = b2base + (size_t)(srow + 16) * D_DIM + (s1 << 3);
  ushort_t* lA0 = la + (wid << 10);           // 16 rows x 64 B = 1024 B per gll
  ushort_t* lA1 = la + (wid << 10) + 512;
  ushort_t* lB1a = lb1 + (wid << 10);
  ushort_t* lB1b = lb1 + (wid << 10) + 512;
  ushort_t* lB2a = lb2 + (wid << 10);
  ushort_t* lB2b = lb2 + (wid << 10) + 512;

  // --- fixed per-lane fragment read offsets (swizzled) ---
  int wm = (wid >> 1) << 6, wn = (wid & 1) << 6;
  int rsel = lane & 15, g = lane >> 4;
  int offA[4], offB[4];
#pragma unroll
  for (int i = 0; i < 4; i++) {
    int R = wm + i * 16 + rsel;
    offA[i] = (R << 5) + ((g ^ ((R >> 1) & 3)) << 3);
    int R2 = wn + i * 16 + rsel;
    offB[i] = (R2 << 5) + ((g ^ ((R2 >> 1) & 3)) << 3);
  }

  f32x4 acc1[4][4] = {{{0.f}}}, acc2[4][4] = {{{0.f}}};
  for (int k0 = 0; k0 < D_DIM; k0 += BK) {
    GLL16(gA0, lA0);   GLL16(gA1, lA1);
    GLL16(gB1a, lB1a); GLL16(gB1b, lB1b);
    GLL16(gB2a, lB2a); GLL16(gB2b, lB2b);
    gA0 += BK; gA1 += BK; gB1a += BK; gB1b += BK; gB2a += BK; gB2b += BK;
    __syncthreads();
    short8 af[4], bf1[4], bf2[4];
#pragma unroll
    for (int i = 0; i < 4; i++) {
      af[i]  = *(const short8*)&la[offA[i]];
      bf1[i] = *(const short8*)&lb1[offB[i]];
      bf2[i] = *(const short8*)&lb2[offB[i]];
    }
#pragma unroll
    for (int mi = 0; mi < 4; mi++)
#pragma unroll
      for (int ni = 0; ni < 4; ni++) {
        acc1[mi][ni] = __builtin_amdgcn_mfma_f32_16x16x32_bf16(af[mi], bf1[ni], acc1[mi][ni], 0, 0, 0);
        acc2[mi][ni] = __builtin_amdgcn_mfma_f32_16x16x32_bf16(af[mi], bf2[ni], acc2[mi][ni], 0, 0, 0);
      }
    __syncthreads();
  }
  int cw = lane & 15, rw = (lane >> 4) << 2;
#pragma unroll
  for (int mi = 0; mi < 4; mi++)
#pragma unroll
    for (int ni = 0; ni < 4; ni++)
#pragma unroll
      for (int r = 0; r < 4; r++) {
        int lrow = wm + mi * 16 + rw + r;
        int col = n0 + wn + ni * 16 + cw;
        float gg = acc1[mi][ni][r], u = acc2[mi][ni][r];
        float h = gg * (1.f / (1.f + __expf(-gg))) * u;
        dst[(rowbase + lrow) * (size_t)dstride + col] = f2bf(h);
      }
}

// ---------------- fused down-proj: gll staging, all atomicAdd ----------------
__global__ __launch_bounds__(256, 2)
void down_gemm(const ushort_t* __restrict__ hsh, const ushort_t* __restrict__ hbuf,
               const ushort_t* __restrict__ sdb, const ushort_t* __restrict__ w2b,
               const int* __restrict__ toklist, const float* __restrict__ ew,
               const int4* __restrict__ assign, const int* __restrict__ meta,
               float* __restrict__ out) {
  __shared__ ushort_t la[BM * BK], lb[BN * BK];
  __shared__ int ttok[BM];
  __shared__ float twt[BM];
  int bid = blockIdx.x;
  int tid = threadIdx.x, wid = tid >> 6, lane = tid & 63;

  const ushort_t *abase, *bbase;
  int n0, kend;

  if (bid < DN_SHARED_BLOCKS) {
    int m0 = (bid >> 3) * BM;
    n0 = (bid & 7) * BN;
    abase = hsh + (size_t)m0 * SH_DIM;
    bbase = sdb + (size_t)n0 * SH_DIM;
    kend = SH_DIM;
    if (tid < BM) { ttok[tid] = m0 + tid; twt[tid] = 1.f; }
  } else {
    int rid = bid - DN_SHARED_BLOCKS;
    int tidx = rid >> 3;
    if (tidx >= meta[0]) return;
    int4 as = assign[tidx];
    int e = as.x, tile = as.y, sbase = as.z, cnt = as.w;
    n0 = (rid & 7) * BN;
    abase = hbuf + ((size_t)sbase + (size_t)tile * BM) * F_DIM;
    bbase = w2b + ((size_t)e * D_DIM + n0) * F_DIM;
    kend = F_DIM;
    if (tid < BM) {
      int idx = tile * BM + tid;
      int tk = (idx < cnt) ? toklist[e * T_TOK + idx] : -1;
      ttok[tid] = tk;
      twt[tid] = (tk >= 0) ? ew[tk * E_NUM + e] : 0.f;
    }
  }
  __syncthreads();

  int srow = (wid << 5) + (lane >> 2);
  int c16 = lane & 3;
  int s0 = c16 ^ ((srow >> 1) & 3);
  int s1 = c16 ^ (((srow + 16) >> 1) & 3);
  const ushort_t* gA0 = abase + (size_t)srow * kend + (s0 << 3);
  const ushort_t* gA1 = abase + (size_t)(srow + 16) * kend + (s1 << 3);
  const ushort_t* gB0 = bbase + (size_t)srow * kend + (s0 << 3);
  const ushort_t* gB1 = bbase + (size_t)(srow + 16) * kend + (s1 << 3);
  ushort_t* lA0 = la + (wid << 10);
  ushort_t* lA1 = la + (wid << 10) + 512;
  ushort_t* lB0 = lb + (wid << 10);
  ushort_t* lB1 = lb + (wid << 10) + 512;

  int wm = (wid >> 1) << 6, wn = (wid & 1) << 6;
  int rsel = lane & 15, g = lane >> 4;
  int offA[4], offB[4];
#pragma unroll
  for (int i = 0; i < 4; i++) {
    int R = wm + i * 16 + rsel;
    offA[i] = (R << 5) + ((g ^ ((R >> 1) & 3)) << 3);
    int R2 = wn + i * 16 + rsel;
    offB[i] = (R2 << 5) + ((g ^ ((R2 >> 1) & 3)) << 3);
  }

  f32x4 acc[4][4] = {{{0.f}}};
  for (int k0 = 0; k0 < kend; k0 += BK) {
    GLL16(gA0, lA0); GLL16(gA1, lA1);
    GLL16(gB0, lB0); GLL16(gB1, lB1);
    gA0 += BK; gA1 += BK; gB0 += BK; gB1 += BK;
    __syncthreads();
    short8 af[4], bf[4];
#pragma unroll
    for (int i = 0; i < 4; i++) {
      af[i] = *(const short8*)&la[offA[i]];
      bf[i] = *(const short8*)&lb[offB[i]];
    }
#pragma unroll
    for (int mi = 0; mi < 4; mi++)
#pragma unroll
      for (int ni = 0; ni < 4; ni++)
        acc[mi][ni] = __builtin_amdgcn_mfma_f32_16x16x32_bf16(af[mi], bf[ni], acc[mi][ni], 0, 0, 0);
    __syncthreads();
  }
  int cw = lane & 15, rw = (lane >> 4) << 2;
#pragma unroll
  for (int mi = 0; mi < 4; mi++)
#pragma unroll
    for (int ni = 0; ni < 4; ni++)
#pragma unroll
      for (int r = 0; r < 4; r++) {
        int lrow = wm + mi * 16 + rw + r;
        int tk = ttok[lrow];
        if (tk >= 0) {
          int col = n0 + wn + ni * 16 + cw;
          atomicAdd(&out[(size_t)tk * D_DIM + col], twt[lrow] * acc[mi][ni][r]);
        }
      }
}

extern "C" void kernel_launch(void* const* d_in, const int* in_sizes, int n_in,
                              void* d_out, int out_size, void* d_ws, size_t ws_size,
                              hipStream_t stream) {
  const float* x  = (const float*)d_in[0];
  const float* gw = (const float*)d_in[1];
  const float* gb = (const float*)d_in[2];
  const float* w1 = (const float*)d_in[3];
  const float* w2 = (const float*)d_in[4];
  const float* w3 = (const float*)d_in[5];
  const float* sg = (const float*)d_in[6];
  const float* su = (const float*)d_in[7];
  const float* sd = (const float*)d_in[8];
  float* out = (float*)d_out;

  char* ws = (char*)d_ws;
  size_t off = 0;
  auto alloc = [&](size_t bytes) {
    char* p = ws + off;
    off += (bytes + 255) & ~(size_t)255;
    return p;
  };
  ushort_t* xb   = (ushort_t*)alloc((size_t)T_TOK * D_DIM * 2);
  ushort_t* w1b  = (ushort_t*)alloc((size_t)NBIG * 2);
  ushort_t* w2b  = (ushort_t*)alloc((size_t)NBIG * 2);
  ushort_t* w3b  = (ushort_t*)alloc((size_t)NBIG * 2);
  ushort_t* sgb  = (ushort_t*)alloc((size_t)NSML * 2);
  ushort_t* sub  = (ushort_t*)alloc((size_t)NSML * 2);
  ushort_t* sdb  = (ushort_t*)alloc((size_t)NSML * 2);
  float*    ew   = (float*)alloc((size_t)T_TOK * E_NUM * 4);
  ushort_t* hsh  = (ushort_t*)alloc((size_t)T_TOK * SH_DIM * 2);
  ushort_t* hbuf = (ushort_t*)alloc((size_t)MAX_TILES * BM * F_DIM * 2);
  int*      toklist = (int*)alloc((size_t)E_NUM * T_TOK * 4);
  int*      counts  = (int*)alloc(64);
  int4*     assign  = (int4*)alloc((MAX_TILES + 8) * sizeof(int4));
  int*      meta    = (int*)alloc(64);

  hipMemsetAsync(counts, 0, 64, stream);
  hipMemsetAsync(out, 0, (size_t)out_size * sizeof(float), stream);
  gate_kernel<<<T_TOK, 64, 0, stream>>>(x, gw, gb, ew, xb);
  convert_kernel<<<NCONV_CHUNKS / 256, 256, 0, stream>>>(w1, w2, w3, sg, su, sd,
                                                         w1b, w2b, w3b, sgb, sub, sdb);
  build_lists<<<(T_TOK + 255) / 256, 256, 0, stream>>>(ew, counts, toklist);
  assign_kernel<<<1, 64, 0, stream>>>(counts, assign, meta);
  up_gemm<<<UP_TOTAL, 256, 0, stream>>>(xb, sgb, sub, w1b, w3b, toklist, assign, meta,
                                        hsh, hbuf);
  down_gemm<<<DN_TOTAL, 256, 0, stream>>>(hsh, hbuf, sdb, w2b, toklist, ew, assign, meta,
                                          out);
}